// Round 1
// baseline (160.684 us; speedup 1.0000x reference)
//
#include <hip/hip_runtime.h>
#include <math.h>

// Converse2D (USRNet closed-form prox), s=2, B=4, C=64, H=W=128, K=5.
// Per (b,c): 1 fwd 128x128 FFT, then two {K-mult + inv FFT} passes packing the
// 4 output polyphases. Fused radix-2 stage pairs (radix-4 traffic), float2 LDS.
//
// R1 change: precompute_K previously stored at bit-reversed addresses
// (8-byte scatter at 16B stride over 1KB spans -> ~8 half-line transactions
// per wave-store + RMW), costing ~77us. Bit-reversal is an involution, so we
// now iterate contiguously over the OUTPUT index and bit-reverse the INPUT
// (q,r) instead: identical table contents, fully coalesced stores.

struct cx { float x, y; };
__device__ __forceinline__ cx cmul(cx a, cx b){ return cx{a.x*b.x - a.y*b.y, a.x*b.y + a.y*b.x}; }
__device__ __forceinline__ cx cadd(cx a, cx b){ return cx{a.x+b.x, a.y+b.y}; }
__device__ __forceinline__ cx csub(cx a, cx b){ return cx{a.x-b.x, a.y-b.y}; }
__device__ __forceinline__ cx cconj(cx a){ return cx{a.x, -a.y}; }
__device__ __forceinline__ cx cscale(cx a, float s){ return cx{a.x*s, a.y*s}; }

__device__ __forceinline__ float2 cmulf(float2 a, float2 b){
    return make_float2(a.x*b.x - a.y*b.y, a.x*b.y + a.y*b.x);
}
__device__ __forceinline__ float2 cmulcf(float2 a, float2 b){ // a * conj(b)
    return make_float2(a.x*b.x + a.y*b.y, a.y*b.x - a.x*b.y);
}
__device__ __forceinline__ float2 caddf(float2 a, float2 b){ return make_float2(a.x+b.x, a.y+b.y); }
__device__ __forceinline__ float2 csubf(float2 a, float2 b){ return make_float2(a.x-b.x, a.y-b.y); }

// H_p(q,r) for the 4 output phases, table-based twiddles.
// TAB[k] = e^{-2*pi*i*k/256}
__device__ __forceinline__ void compute_H_tab(const float* __restrict__ wc, float lam,
                                              int q, int r, const float2* __restrict__ TAB,
                                              cx H[4])
{
    cx er[5], eq[5];
    #pragma unroll
    for (int t = 0; t < 5; ++t) {
        float2 a = TAB[(r * (t - 2)) & 255];
        er[t] = cx{a.x, a.y};
        float2 b = TAB[(q * (t - 2)) & 255];
        eq[t] = cx{b.x, b.y};
    }
    cx P0[5], P1[5];
    #pragma unroll
    for (int a = 0; a < 5; ++a) {
        cx p0{0.f,0.f}, p1{0.f,0.f};
        #pragma unroll
        for (int b = 0; b < 5; ++b) {
            cx t = cscale(er[b], wc[a*5 + b]);
            p0 = cadd(p0, t);
            p1 = (b & 1) ? csub(p1, t) : cadd(p1, t);
        }
        P0[a] = p0; P1[a] = p1;
    }
    cx F[2][2];
    F[0][0]=cx{0.f,0.f}; F[0][1]=cx{0.f,0.f}; F[1][0]=cx{0.f,0.f}; F[1][1]=cx{0.f,0.f};
    #pragma unroll
    for (int a = 0; a < 5; ++a) {
        cx t0 = cmul(eq[a], P0[a]);
        cx t1 = cmul(eq[a], P1[a]);
        F[0][0] = cadd(F[0][0], t0); F[0][1] = cadd(F[0][1], t1);
        if (a & 1) { F[1][0] = csub(F[1][0], t0); F[1][1] = csub(F[1][1], t1); }
        else       { F[1][0] = cadd(F[1][0], t0); F[1][1] = cadd(F[1][1], t1); }
    }
    float cq = TAB[q].x, sq = TAB[q].y;   // (cos, -sin) of 2*pi*q/256
    float cr = TAB[r].x, sr = TAB[r].y;
    cx Du[2] = { cx{1.f+cq,  sq}, cx{1.f-cq, -sq} };
    cx Dv[2] = { cx{1.f+cr,  sr}, cx{1.f-cr, -sr} };
    cx R[2][2];
    float invW = 0.f;
    cx M{0.f,0.f};
    #pragma unroll
    for (int i = 0; i < 2; ++i)
      #pragma unroll
      for (int k = 0; k < 2; ++k) {
        cx fb = F[i][k];
        cx Rik = cadd(cconj(fb), cscale(cmul(Du[i], Dv[k]), lam));
        R[i][k] = Rik;
        invW += 0.25f * (fb.x*fb.x + fb.y*fb.y);
        M = cadd(M, cscale(cmul(fb, Rik), 0.25f));
      }
    cx V = cscale(M, 1.0f / (invW + lam));
    float inv_lam = 1.0f / lam;
    cx G[2][2];
    #pragma unroll
    for (int i = 0; i < 2; ++i)
      #pragma unroll
      for (int k = 0; k < 2; ++k)
        G[i][k] = cscale(csub(R[i][k], cmul(cconj(F[i][k]), V)), inv_lam);

    cx G00 = G[0][0], G01 = G[0][1], G10 = G[1][0], G11 = G[1][1];
    cx Gh00 = cadd(cadd(G00,G01), cadd(G10,G11));
    cx Gh01 = cadd(csub(G00,G01), csub(G10,G11));
    cx Gh10 = csub(cadd(G00,G01), cadd(G10,G11));
    cx Gh11 = csub(csub(G00,G01), csub(G10,G11));
    cx phq = cx{cq, -sq};
    cx phr = cx{cr, -sr};
    H[0] = Gh00;
    H[1] = cmul(Gh01, phr);
    H[2] = cmul(Gh10, phq);
    H[3] = cmul(Gh11, cmul(phq, phr));
}

__global__ __launch_bounds__(256)
void precompute_K(const float* __restrict__ weight, const float* __restrict__ lam_ptr,
                  float2* __restrict__ KA, float2* __restrict__ KB)
{
    __shared__ float2 TAB[256];
    __shared__ float WC[25];
    const int tid = threadIdx.x;
    {
        float s_, c_;
        __sincosf(-6.28318530717958647692f * (float)tid * (1.0f/256.0f), &s_, &c_);
        TAB[tid] = make_float2(c_, s_);
    }
    const int c = blockIdx.x >> 4;           // 1024 blocks: 16 per channel (4/CU)
    if (tid < 25) WC[tid] = weight[c*25 + tid];
    __syncthreads();
    const float lam = lam_ptr[0];
    const int nbase = (blockIdx.x & 15) * 1024;
    const float scale = 1.0f / 65536.0f;     // ifft 1/(128*128) and 1/4 polyphase mean

    #pragma unroll 1
    for (int k = 0; k < 4; ++k) {
        // idx walks the OUTPUT (bit-reversed-domain) table contiguously;
        // bit-reverse on the input side: store[i][j] = H(brev7(i), brev7(j)).
        int idx = nbase + k*256 + tid;
        int qb = idx >> 7, rb = idx & 127;
        int q = (int)(__brev((unsigned)qb) >> 25);
        int r = (int)(__brev((unsigned)rb) >> 25);
        cx H[4];
        compute_H_tab(WC, lam, q, r, TAB, H);
        // H is exactly Hermitian on the 128-grid (proved: every factor conjugates
        // under (q,r)->(-q,-r)), so no symmetrization needed.
        float2 kAv = make_float2((H[0].x - H[1].y)*scale, (H[0].y + H[1].x)*scale);
        float2 kBv = make_float2((H[2].x - H[3].y)*scale, (H[2].y + H[3].x)*scale);
        int o = (c << 14) + idx;             // contiguous across tid -> coalesced
        KA[o] = kAv;
        KB[o] = kBv;
    }
}

#define ST2 129   // float2 stride: odd -> both row & col passes at bank-bandwidth minimum

template<int AXIS> __device__ __forceinline__ int laddr(int line, int i){
    return AXIS ? (i*ST2 + line) : (line*ST2 + i);
}

// Forward DIF, fused stages (S, S+1). S in {0,2,4}. 4096 quartets, 4/thread.
template<int AXIS, int S>
__device__ __forceinline__ void fwd_pair(float2* Sm, const float2* TW, int tid)
{
    const int h  = 64 >> S;
    const int hh = 32 >> S;
    #pragma unroll
    for (int it = 0; it < 4; ++it) {
        int qid  = it*1024 + tid;
        int line = qid & 127;
        int t    = qid >> 7;
        int blk  = t >> (5 - S);
        int j    = t & (hh - 1);
        int i0   = (blk << (7 - S)) + j;
        int a0 = laddr<AXIS>(line, i0);
        int a1 = laddr<AXIS>(line, i0 + hh);
        int a2 = laddr<AXIS>(line, i0 + h);
        int a3 = laddr<AXIS>(line, i0 + h + hh);
        float2 e0 = Sm[a0], e1 = Sm[a1], e2 = Sm[a2], e3 = Sm[a3];
        float2 w0 = TW[j << S], w1 = TW[(j << S) + 32], w2 = TW[j << (S + 1)];
        float2 u0 = caddf(e0, e2), d0 = cmulf(csubf(e0, e2), w0);
        float2 u1 = caddf(e1, e3), d1 = cmulf(csubf(e1, e3), w1);
        Sm[a0] = caddf(u0, u1);
        Sm[a1] = cmulf(csubf(u0, u1), w2);
        Sm[a2] = caddf(d0, d1);
        Sm[a3] = cmulf(csubf(d0, d1), w2);
    }
}

// Inverse DIT, fused stages (S, S+1). S in {0..5 odd/even as called}. conj twiddles.
template<int AXIS, int S>
__device__ __forceinline__ void inv_pair(float2* Sm, const float2* TW, int tid)
{
    const int h = 1 << S;
    #pragma unroll
    for (int it = 0; it < 4; ++it) {
        int qid  = it*1024 + tid;
        int line = qid & 127;
        int t    = qid >> 7;
        int blk  = t >> S;
        int j    = t & (h - 1);
        int base = (blk << (S + 2)) + j;
        int a0 = laddr<AXIS>(line, base);
        int a1 = laddr<AXIS>(line, base + h);
        int a2 = laddr<AXIS>(line, base + 2*h);
        int a3 = laddr<AXIS>(line, base + 3*h);
        float2 e0 = Sm[a0], e1 = Sm[a1], e2 = Sm[a2], e3 = Sm[a3];
        float2 cw0 = TW[j << (6 - S)];
        float2 cw1 = TW[j << (5 - S)];
        float2 cw2 = TW[(j << (5 - S)) + 32];
        float2 t1 = cmulcf(e1, cw0);
        float2 A0 = caddf(e0, t1), A1 = csubf(e0, t1);
        float2 t2 = cmulcf(e3, cw0);
        float2 A2 = caddf(e2, t2), A3 = csubf(e2, t2);
        float2 u = cmulcf(A2, cw1);
        Sm[a0] = caddf(A0, u);
        Sm[a2] = csubf(A0, u);
        float2 v = cmulcf(A3, cw2);
        Sm[a1] = caddf(A1, v);
        Sm[a3] = csubf(A1, v);
    }
}

__global__ __launch_bounds__(1024)
void converse_main(const float* __restrict__ x, const float* __restrict__ bias,
                   const float2* __restrict__ KA, const float2* __restrict__ KB,
                   float* __restrict__ out)
{
    __shared__ float2 S[128 * ST2];
    __shared__ float2 TW[64];

    const int tid = threadIdx.x;
    const int bc  = blockIdx.x;       // [0,256) = b*64 + c
    const int c   = bc & 63;

    if (tid < 64) {
        float s_, c_;
        __sincosf(-6.28318530717958647692f * (float)tid * (1.0f/128.0f), &s_, &c_);
        TW[tid] = make_float2(c_, s_);
    }

    // ---- load x[b,c] as {x, 0} (contiguous float2 writes, conflict-free) ----
    const float* xp = x + (size_t)bc * 16384;
    #pragma unroll
    for (int it = 0; it < 16; ++it) {
        int n = it * 1024 + tid;
        S[(n >> 7) * ST2 + (n & 127)] = make_float2(xp[n], 0.0f);
    }
    __syncthreads();

    // ---- forward rows (along n): fused (0,1),(2,3),(4,5), single 6 ----
    fwd_pair<0,0>(S, TW, tid); __syncthreads();
    fwd_pair<0,2>(S, TW, tid); __syncthreads();
    fwd_pair<0,4>(S, TW, tid); __syncthreads();
    #pragma unroll
    for (int it = 0; it < 8; ++it) {     // stage 6: pairs (2k,2k+1), twiddle 1
        int g = it*1024 + tid;
        int line = g & 127, k = g >> 7;
        int a = line*ST2 + 2*k;
        float2 u = S[a], v = S[a+1];
        S[a]   = caddf(u, v);
        S[a+1] = csubf(u, v);
    }
    __syncthreads();

    // ---- forward cols (along m): fused (0,1),(2,3),(4,5) ----
    fwd_pair<1,0>(S, TW, tid); __syncthreads();
    fwd_pair<1,2>(S, TW, tid); __syncthreads();
    fwd_pair<1,4>(S, TW, tid); __syncthreads();

    // ---- forward col stage 6 into registers (spectrum kept for both passes) ----
    float2 sA[8], sB[8];
    #pragma unroll
    for (int it = 0; it < 8; ++it) {
        int g = it*1024 + tid;
        int nn = g & 127, j = g >> 7;
        int a = (2*j)*ST2 + nn;
        float2 u = S[a], v = S[a + ST2];
        sA[it] = caddf(u, v);
        sB[it] = csubf(u, v);
    }
    // no barrier needed: each thread re-writes only its own addresses in the mult

    const float bv = bias[c];
    float* op = out + (size_t)bc * 65536;

    #pragma unroll 1
    for (int pass = 0; pass < 2; ++pass) {
        // ---- K-mult (from regs) fused with inverse col stage 0 (h=1, w=1) ----
        const float2* Kp = (pass ? KB : KA) + (size_t)c * 16384;
        #pragma unroll
        for (int it = 0; it < 8; ++it) {
            int g = it*1024 + tid;
            int nn = g & 127, j = g >> 7;
            float2 kA = Kp[(j << 8) + nn];
            float2 kB = Kp[(j << 8) + 128 + nn];
            float2 w0 = cmulf(sA[it], kA);
            float2 w1 = cmulf(sB[it], kB);
            int a = (2*j)*ST2 + nn;
            S[a]       = caddf(w0, w1);
            S[a + ST2] = csubf(w0, w1);
        }
        __syncthreads();

        // ---- inverse cols: fused (1,2),(3,4),(5,6) ----
        inv_pair<1,1>(S, TW, tid); __syncthreads();
        inv_pair<1,3>(S, TW, tid); __syncthreads();
        inv_pair<1,5>(S, TW, tid); __syncthreads();

        // ---- inverse rows: fused (0,1),(2,3),(4,5) ----
        inv_pair<0,0>(S, TW, tid); __syncthreads();
        inv_pair<0,2>(S, TW, tid); __syncthreads();
        inv_pair<0,4>(S, TW, tid); __syncthreads();

        // ---- inverse row stage 6 fused with store (Re->even col, Im->odd col) ----
        #pragma unroll
        for (int it = 0; it < 8; ++it) {
            int g = it*1024 + tid;
            int j = g & 63, m = g >> 6;
            int a = m*ST2 + j;
            float2 u = S[a], v = S[a + 64];
            float2 t = cmulcf(v, TW[j]);
            float2 o0 = caddf(u, t);
            float2 o1 = csubf(u, t);
            size_t ro = (size_t)(2*m + pass) * 256;
            *(float2*)(op + ro + 2*j)       = make_float2(o0.x + bv, o0.y + bv);
            *(float2*)(op + ro + 2*j + 128) = make_float2(o1.x + bv, o1.y + bv);
        }
        __syncthreads();   // protect S from next pass's mult writes
    }
}

extern "C" void kernel_launch(void* const* d_in, const int* in_sizes, int n_in,
                              void* d_out, int out_size, void* d_ws, size_t ws_size,
                              hipStream_t stream)
{
    const float* x      = (const float*)d_in[0];   // [4,64,128,128]
    const float* weight = (const float*)d_in[1];   // [1,64,5,5]
    const float* bias   = (const float*)d_in[2];   // [1,64,1,1]
    const float* lam    = (const float*)d_in[3];   // [1,1,1,1]
    float* out = (float*)d_out;                    // [4,64,256,256]

    float2* KA = (float2*)d_ws;                    // 8 MB
    float2* KB = KA + (size_t)64 * 16384;          // 8 MB

    hipLaunchKernelGGL(precompute_K, dim3(1024), dim3(256), 0, stream,
                       weight, lam, KA, KB);
    hipLaunchKernelGGL(converse_main, dim3(256), dim3(1024), 0, stream,
                       x, bias, KA, KB, out);
}

// Round 2
// 159.180 us; speedup vs baseline: 1.0094x; 1.0094x over previous
//
#include <hip/hip_runtime.h>
#include <math.h>

// Converse2D (USRNet closed-form prox), s=2, B=4, C=64, H=W=128, K=5.
// Per (b,c): 1 fwd 128x128 FFT, then two {K-mult + inv FFT} passes packing the
// 4 output polyphases. Fused radix-2 stage pairs (radix-4 traffic), float2 LDS.
//
// R1: precompute_K stores made output-contiguous (bit-reverse the INPUT (q,r),
//     involution => identical table), coalesced stores.
// R2: register-budget fix. rocprof showed converse_main at VGPR_Count=64 with
//     WRITE_SIZE 118MB (out is only 64MB) and FETCH 67MB (~32MB ideal): scratch
//     spill/reload of the sA/sB spectrum registers. The 132KB LDS caps the CU
//     at ONE 1024-thread block (= 4 waves/SIMD), so the default 8-wave/SIMD
//     register budget (64 VGPR) was pure waste. __launch_bounds__(1024,4)
//     raises the cap to 128 VGPR -> no spills. Same for precompute_K
//     (compute_H_tab has ~90 live VGPRs): __launch_bounds__(256,4).

struct cx { float x, y; };
__device__ __forceinline__ cx cmul(cx a, cx b){ return cx{a.x*b.x - a.y*b.y, a.x*b.y + a.y*b.x}; }
__device__ __forceinline__ cx cadd(cx a, cx b){ return cx{a.x+b.x, a.y+b.y}; }
__device__ __forceinline__ cx csub(cx a, cx b){ return cx{a.x-b.x, a.y-b.y}; }
__device__ __forceinline__ cx cconj(cx a){ return cx{a.x, -a.y}; }
__device__ __forceinline__ cx cscale(cx a, float s){ return cx{a.x*s, a.y*s}; }

__device__ __forceinline__ float2 cmulf(float2 a, float2 b){
    return make_float2(a.x*b.x - a.y*b.y, a.x*b.y + a.y*b.x);
}
__device__ __forceinline__ float2 cmulcf(float2 a, float2 b){ // a * conj(b)
    return make_float2(a.x*b.x + a.y*b.y, a.y*b.x - a.x*b.y);
}
__device__ __forceinline__ float2 caddf(float2 a, float2 b){ return make_float2(a.x+b.x, a.y+b.y); }
__device__ __forceinline__ float2 csubf(float2 a, float2 b){ return make_float2(a.x-b.x, a.y-b.y); }

// H_p(q,r) for the 4 output phases, table-based twiddles.
// TAB[k] = e^{-2*pi*i*k/256}
__device__ __forceinline__ void compute_H_tab(const float* __restrict__ wc, float lam,
                                              int q, int r, const float2* __restrict__ TAB,
                                              cx H[4])
{
    cx er[5], eq[5];
    #pragma unroll
    for (int t = 0; t < 5; ++t) {
        float2 a = TAB[(r * (t - 2)) & 255];
        er[t] = cx{a.x, a.y};
        float2 b = TAB[(q * (t - 2)) & 255];
        eq[t] = cx{b.x, b.y};
    }
    cx P0[5], P1[5];
    #pragma unroll
    for (int a = 0; a < 5; ++a) {
        cx p0{0.f,0.f}, p1{0.f,0.f};
        #pragma unroll
        for (int b = 0; b < 5; ++b) {
            cx t = cscale(er[b], wc[a*5 + b]);
            p0 = cadd(p0, t);
            p1 = (b & 1) ? csub(p1, t) : cadd(p1, t);
        }
        P0[a] = p0; P1[a] = p1;
    }
    cx F[2][2];
    F[0][0]=cx{0.f,0.f}; F[0][1]=cx{0.f,0.f}; F[1][0]=cx{0.f,0.f}; F[1][1]=cx{0.f,0.f};
    #pragma unroll
    for (int a = 0; a < 5; ++a) {
        cx t0 = cmul(eq[a], P0[a]);
        cx t1 = cmul(eq[a], P1[a]);
        F[0][0] = cadd(F[0][0], t0); F[0][1] = cadd(F[0][1], t1);
        if (a & 1) { F[1][0] = csub(F[1][0], t0); F[1][1] = csub(F[1][1], t1); }
        else       { F[1][0] = cadd(F[1][0], t0); F[1][1] = cadd(F[1][1], t1); }
    }
    float cq = TAB[q].x, sq = TAB[q].y;   // (cos, -sin) of 2*pi*q/256
    float cr = TAB[r].x, sr = TAB[r].y;
    cx Du[2] = { cx{1.f+cq,  sq}, cx{1.f-cq, -sq} };
    cx Dv[2] = { cx{1.f+cr,  sr}, cx{1.f-cr, -sr} };
    cx R[2][2];
    float invW = 0.f;
    cx M{0.f,0.f};
    #pragma unroll
    for (int i = 0; i < 2; ++i)
      #pragma unroll
      for (int k = 0; k < 2; ++k) {
        cx fb = F[i][k];
        cx Rik = cadd(cconj(fb), cscale(cmul(Du[i], Dv[k]), lam));
        R[i][k] = Rik;
        invW += 0.25f * (fb.x*fb.x + fb.y*fb.y);
        M = cadd(M, cscale(cmul(fb, Rik), 0.25f));
      }
    cx V = cscale(M, 1.0f / (invW + lam));
    float inv_lam = 1.0f / lam;
    cx G[2][2];
    #pragma unroll
    for (int i = 0; i < 2; ++i)
      #pragma unroll
      for (int k = 0; k < 2; ++k)
        G[i][k] = cscale(csub(R[i][k], cmul(cconj(F[i][k]), V)), inv_lam);

    cx G00 = G[0][0], G01 = G[0][1], G10 = G[1][0], G11 = G[1][1];
    cx Gh00 = cadd(cadd(G00,G01), cadd(G10,G11));
    cx Gh01 = cadd(csub(G00,G01), csub(G10,G11));
    cx Gh10 = csub(cadd(G00,G01), cadd(G10,G11));
    cx Gh11 = csub(csub(G00,G01), csub(G10,G11));
    cx phq = cx{cq, -sq};
    cx phr = cx{cr, -sr};
    H[0] = Gh00;
    H[1] = cmul(Gh01, phr);
    H[2] = cmul(Gh10, phq);
    H[3] = cmul(Gh11, cmul(phq, phr));
}

__global__ __launch_bounds__(256, 4)
void precompute_K(const float* __restrict__ weight, const float* __restrict__ lam_ptr,
                  float2* __restrict__ KA, float2* __restrict__ KB)
{
    __shared__ float2 TAB[256];
    __shared__ float WC[25];
    const int tid = threadIdx.x;
    {
        float s_, c_;
        __sincosf(-6.28318530717958647692f * (float)tid * (1.0f/256.0f), &s_, &c_);
        TAB[tid] = make_float2(c_, s_);
    }
    const int c = blockIdx.x >> 4;           // 1024 blocks: 16 per channel (4/CU)
    if (tid < 25) WC[tid] = weight[c*25 + tid];
    __syncthreads();
    const float lam = lam_ptr[0];
    const int nbase = (blockIdx.x & 15) * 1024;
    const float scale = 1.0f / 65536.0f;     // ifft 1/(128*128) and 1/4 polyphase mean

    #pragma unroll 1
    for (int k = 0; k < 4; ++k) {
        // idx walks the OUTPUT (bit-reversed-domain) table contiguously;
        // bit-reverse on the input side: store[i][j] = H(brev7(i), brev7(j)).
        int idx = nbase + k*256 + tid;
        int qb = idx >> 7, rb = idx & 127;
        int q = (int)(__brev((unsigned)qb) >> 25);
        int r = (int)(__brev((unsigned)rb) >> 25);
        cx H[4];
        compute_H_tab(WC, lam, q, r, TAB, H);
        // H is exactly Hermitian on the 128-grid (proved: every factor conjugates
        // under (q,r)->(-q,-r)), so no symmetrization needed.
        float2 kAv = make_float2((H[0].x - H[1].y)*scale, (H[0].y + H[1].x)*scale);
        float2 kBv = make_float2((H[2].x - H[3].y)*scale, (H[2].y + H[3].x)*scale);
        int o = (c << 14) + idx;             // contiguous across tid -> coalesced
        KA[o] = kAv;
        KB[o] = kBv;
    }
}

#define ST2 129   // float2 stride: odd -> both row & col passes at bank-bandwidth minimum

template<int AXIS> __device__ __forceinline__ int laddr(int line, int i){
    return AXIS ? (i*ST2 + line) : (line*ST2 + i);
}

// Forward DIF, fused stages (S, S+1). S in {0,2,4}. 4096 quartets, 4/thread.
template<int AXIS, int S>
__device__ __forceinline__ void fwd_pair(float2* Sm, const float2* TW, int tid)
{
    const int h  = 64 >> S;
    const int hh = 32 >> S;
    #pragma unroll
    for (int it = 0; it < 4; ++it) {
        int qid  = it*1024 + tid;
        int line = qid & 127;
        int t    = qid >> 7;
        int blk  = t >> (5 - S);
        int j    = t & (hh - 1);
        int i0   = (blk << (7 - S)) + j;
        int a0 = laddr<AXIS>(line, i0);
        int a1 = laddr<AXIS>(line, i0 + hh);
        int a2 = laddr<AXIS>(line, i0 + h);
        int a3 = laddr<AXIS>(line, i0 + h + hh);
        float2 e0 = Sm[a0], e1 = Sm[a1], e2 = Sm[a2], e3 = Sm[a3];
        float2 w0 = TW[j << S], w1 = TW[(j << S) + 32], w2 = TW[j << (S + 1)];
        float2 u0 = caddf(e0, e2), d0 = cmulf(csubf(e0, e2), w0);
        float2 u1 = caddf(e1, e3), d1 = cmulf(csubf(e1, e3), w1);
        Sm[a0] = caddf(u0, u1);
        Sm[a1] = cmulf(csubf(u0, u1), w2);
        Sm[a2] = caddf(d0, d1);
        Sm[a3] = cmulf(csubf(d0, d1), w2);
    }
}

// Inverse DIT, fused stages (S, S+1). S in {0..5 odd/even as called}. conj twiddles.
template<int AXIS, int S>
__device__ __forceinline__ void inv_pair(float2* Sm, const float2* TW, int tid)
{
    const int h = 1 << S;
    #pragma unroll
    for (int it = 0; it < 4; ++it) {
        int qid  = it*1024 + tid;
        int line = qid & 127;
        int t    = qid >> 7;
        int blk  = t >> S;
        int j    = t & (h - 1);
        int base = (blk << (S + 2)) + j;
        int a0 = laddr<AXIS>(line, base);
        int a1 = laddr<AXIS>(line, base + h);
        int a2 = laddr<AXIS>(line, base + 2*h);
        int a3 = laddr<AXIS>(line, base + 3*h);
        float2 e0 = Sm[a0], e1 = Sm[a1], e2 = Sm[a2], e3 = Sm[a3];
        float2 cw0 = TW[j << (6 - S)];
        float2 cw1 = TW[j << (5 - S)];
        float2 cw2 = TW[(j << (5 - S)) + 32];
        float2 t1 = cmulcf(e1, cw0);
        float2 A0 = caddf(e0, t1), A1 = csubf(e0, t1);
        float2 t2 = cmulcf(e3, cw0);
        float2 A2 = caddf(e2, t2), A3 = csubf(e2, t2);
        float2 u = cmulcf(A2, cw1);
        Sm[a0] = caddf(A0, u);
        Sm[a2] = csubf(A0, u);
        float2 v = cmulcf(A3, cw2);
        Sm[a1] = caddf(A1, v);
        Sm[a3] = csubf(A1, v);
    }
}

__global__ __launch_bounds__(1024, 4)
void converse_main(const float* __restrict__ x, const float* __restrict__ bias,
                   const float2* __restrict__ KA, const float2* __restrict__ KB,
                   float* __restrict__ out)
{
    __shared__ float2 S[128 * ST2];
    __shared__ float2 TW[64];

    const int tid = threadIdx.x;
    const int bc  = blockIdx.x;       // [0,256) = b*64 + c
    const int c   = bc & 63;

    if (tid < 64) {
        float s_, c_;
        __sincosf(-6.28318530717958647692f * (float)tid * (1.0f/128.0f), &s_, &c_);
        TW[tid] = make_float2(c_, s_);
    }

    // ---- load x[b,c] as {x, 0} (contiguous float2 writes, conflict-free) ----
    const float* xp = x + (size_t)bc * 16384;
    #pragma unroll
    for (int it = 0; it < 16; ++it) {
        int n = it * 1024 + tid;
        S[(n >> 7) * ST2 + (n & 127)] = make_float2(xp[n], 0.0f);
    }
    __syncthreads();

    // ---- forward rows (along n): fused (0,1),(2,3),(4,5), single 6 ----
    fwd_pair<0,0>(S, TW, tid); __syncthreads();
    fwd_pair<0,2>(S, TW, tid); __syncthreads();
    fwd_pair<0,4>(S, TW, tid); __syncthreads();
    #pragma unroll
    for (int it = 0; it < 8; ++it) {     // stage 6: pairs (2k,2k+1), twiddle 1
        int g = it*1024 + tid;
        int line = g & 127, k = g >> 7;
        int a = line*ST2 + 2*k;
        float2 u = S[a], v = S[a+1];
        S[a]   = caddf(u, v);
        S[a+1] = csubf(u, v);
    }
    __syncthreads();

    // ---- forward cols (along m): fused (0,1),(2,3),(4,5) ----
    fwd_pair<1,0>(S, TW, tid); __syncthreads();
    fwd_pair<1,2>(S, TW, tid); __syncthreads();
    fwd_pair<1,4>(S, TW, tid); __syncthreads();

    // ---- forward col stage 6 into registers (spectrum kept for both passes) ----
    float2 sA[8], sB[8];
    #pragma unroll
    for (int it = 0; it < 8; ++it) {
        int g = it*1024 + tid;
        int nn = g & 127, j = g >> 7;
        int a = (2*j)*ST2 + nn;
        float2 u = S[a], v = S[a + ST2];
        sA[it] = caddf(u, v);
        sB[it] = csubf(u, v);
    }
    // no barrier needed: each thread re-writes only its own addresses in the mult

    const float bv = bias[c];
    float* op = out + (size_t)bc * 65536;

    #pragma unroll 1
    for (int pass = 0; pass < 2; ++pass) {
        // ---- K-mult (from regs) fused with inverse col stage 0 (h=1, w=1) ----
        const float2* Kp = (pass ? KB : KA) + (size_t)c * 16384;
        #pragma unroll
        for (int it = 0; it < 8; ++it) {
            int g = it*1024 + tid;
            int nn = g & 127, j = g >> 7;
            float2 kA = Kp[(j << 8) + nn];
            float2 kB = Kp[(j << 8) + 128 + nn];
            float2 w0 = cmulf(sA[it], kA);
            float2 w1 = cmulf(sB[it], kB);
            int a = (2*j)*ST2 + nn;
            S[a]       = caddf(w0, w1);
            S[a + ST2] = csubf(w0, w1);
        }
        __syncthreads();

        // ---- inverse cols: fused (1,2),(3,4),(5,6) ----
        inv_pair<1,1>(S, TW, tid); __syncthreads();
        inv_pair<1,3>(S, TW, tid); __syncthreads();
        inv_pair<1,5>(S, TW, tid); __syncthreads();

        // ---- inverse rows: fused (0,1),(2,3),(4,5) ----
        inv_pair<0,0>(S, TW, tid); __syncthreads();
        inv_pair<0,2>(S, TW, tid); __syncthreads();
        inv_pair<0,4>(S, TW, tid); __syncthreads();

        // ---- inverse row stage 6 fused with store (Re->even col, Im->odd col) ----
        #pragma unroll
        for (int it = 0; it < 8; ++it) {
            int g = it*1024 + tid;
            int j = g & 63, m = g >> 6;
            int a = m*ST2 + j;
            float2 u = S[a], v = S[a + 64];
            float2 t = cmulcf(v, TW[j]);
            float2 o0 = caddf(u, t);
            float2 o1 = csubf(u, t);
            size_t ro = (size_t)(2*m + pass) * 256;
            *(float2*)(op + ro + 2*j)       = make_float2(o0.x + bv, o0.y + bv);
            *(float2*)(op + ro + 2*j + 128) = make_float2(o1.x + bv, o1.y + bv);
        }
        __syncthreads();   // protect S from next pass's mult writes
    }
}

extern "C" void kernel_launch(void* const* d_in, const int* in_sizes, int n_in,
                              void* d_out, int out_size, void* d_ws, size_t ws_size,
                              hipStream_t stream)
{
    const float* x      = (const float*)d_in[0];   // [4,64,128,128]
    const float* weight = (const float*)d_in[1];   // [1,64,5,5]
    const float* bias   = (const float*)d_in[2];   // [1,64,1,1]
    const float* lam    = (const float*)d_in[3];   // [1,1,1,1]
    float* out = (float*)d_out;                    // [4,64,256,256]

    float2* KA = (float2*)d_ws;                    // 8 MB
    float2* KB = KA + (size_t)64 * 16384;          // 8 MB

    hipLaunchKernelGGL(precompute_K, dim3(1024), dim3(256), 0, stream,
                       weight, lam, KA, KB);
    hipLaunchKernelGGL(converse_main, dim3(256), dim3(1024), 0, stream,
                       x, bias, KA, KB, out);
}

// Round 3
// 142.237 us; speedup vs baseline: 1.1297x; 1.1191x over previous
//
#include <hip/hip_runtime.h>
#include <math.h>

// Converse2D (USRNet closed-form prox), s=2, B=4, C=64, H=W=128, K=5.
// Per (b,c): 1 fwd 128x128 FFT, then two {K-mult + inv FFT} passes packing the
// 4 output polyphases. Fused radix-2 stage pairs (radix-4 traffic), float2 LDS.
//
// R1: precompute_K stores made output-contiguous (brev on input side).
// R2: launch_bounds experiment -> no effect (VGPR=64 is true demand, no spill).
// R3: latency de-serialization.
//  (a) converse_main: __syncthreads() drains vmcnt(0) (compiler-emitted), which
//      serialized the x load, both 128KB/block K-table reads and the pass-0
//      store drain against compute. Replace every barrier with
//      {s_waitcnt lgkmcnt(0); s_barrier} only (LDS correctness needs no vmcnt),
//      prefetch KA into 16 float2 regs after x staging (rides across the whole
//      fwd FFT) and KB right after pass-0's mult (rides across pass-0 inverse).
//  (b) precompute_K: no LDS at all; per-point twiddles via __sincosf (same fn
//      that built TAB -> values identical to ~1e-7), 1 point/thread, 4096 blks.

struct cx { float x, y; };
__device__ __forceinline__ cx cmul(cx a, cx b){ return cx{a.x*b.x - a.y*b.y, a.x*b.y + a.y*b.x}; }
__device__ __forceinline__ cx cadd(cx a, cx b){ return cx{a.x+b.x, a.y+b.y}; }
__device__ __forceinline__ cx csub(cx a, cx b){ return cx{a.x-b.x, a.y-b.y}; }
__device__ __forceinline__ cx cconj(cx a){ return cx{a.x, -a.y}; }
__device__ __forceinline__ cx cscale(cx a, float s){ return cx{a.x*s, a.y*s}; }

__device__ __forceinline__ float2 cmulf(float2 a, float2 b){
    return make_float2(a.x*b.x - a.y*b.y, a.x*b.y + a.y*b.x);
}
__device__ __forceinline__ float2 cmulcf(float2 a, float2 b){ // a * conj(b)
    return make_float2(a.x*b.x + a.y*b.y, a.y*b.x - a.x*b.y);
}
__device__ __forceinline__ float2 caddf(float2 a, float2 b){ return make_float2(a.x+b.x, a.y+b.y); }
__device__ __forceinline__ float2 csubf(float2 a, float2 b){ return make_float2(a.x-b.x, a.y-b.y); }

// LDS-only barrier: waits ds ops, leaves global loads/stores in flight.
__device__ __forceinline__ void barrier_lds(){
    __builtin_amdgcn_sched_barrier(0);
    asm volatile("s_waitcnt lgkmcnt(0)" ::: "memory");
    __builtin_amdgcn_s_barrier();
    __builtin_amdgcn_sched_barrier(0);
}

// ---------------- precompute_K: 1 point/thread, no LDS ----------------
__global__ __launch_bounds__(256, 4)
void precompute_K(const float* __restrict__ weight, const float* __restrict__ lam_ptr,
                  float2* __restrict__ KA, float2* __restrict__ KB)
{
    const int tid = threadIdx.x;
    const int c   = blockIdx.x >> 6;                   // 64 blocks per channel
    const int p   = ((blockIdx.x & 63) << 8) + tid;    // 0..16383 (output index)
    const int qb = p >> 7, rb = p & 127;
    const int q = (int)(__brev((unsigned)qb) >> 25);   // brev on INPUT side
    const int r = (int)(__brev((unsigned)rb) >> 25);

    const float th = -6.28318530717958647692f * (1.0f/256.0f);
    float s1,c1, s2,c2, sq1,cq1, sq2,cq2;
    __sincosf(th * (float)r,       &s1,  &c1);
    __sincosf(th * (float)(2*r),   &s2,  &c2);
    __sincosf(th * (float)q,       &sq1, &cq1);
    __sincosf(th * (float)(2*q),   &sq2, &cq2);

    // er[t] = e^{-2*pi*i*r(t-2)/256}, t=0..4 (same values TAB lookups gave)
    cx er[5] = { cx{c2,-s2}, cx{c1,-s1}, cx{1.f,0.f}, cx{c1,s1}, cx{c2,s2} };
    cx eq[5] = { cx{cq2,-sq2}, cx{cq1,-sq1}, cx{1.f,0.f}, cx{cq1,sq1}, cx{cq2,sq2} };

    const float lam = lam_ptr[0];
    const float* wc = weight + c*25;                   // wave-uniform -> s_loads

    cx P0[5], P1[5];
    #pragma unroll
    for (int a = 0; a < 5; ++a) {
        cx p0{0.f,0.f}, p1{0.f,0.f};
        #pragma unroll
        for (int b = 0; b < 5; ++b) {
            cx t = cscale(er[b], wc[a*5 + b]);
            p0 = cadd(p0, t);
            p1 = (b & 1) ? csub(p1, t) : cadd(p1, t);
        }
        P0[a] = p0; P1[a] = p1;
    }
    cx F00{0.f,0.f}, F01{0.f,0.f}, F10{0.f,0.f}, F11{0.f,0.f};
    #pragma unroll
    for (int a = 0; a < 5; ++a) {
        cx t0 = cmul(eq[a], P0[a]);
        cx t1 = cmul(eq[a], P1[a]);
        F00 = cadd(F00, t0); F01 = cadd(F01, t1);
        if (a & 1) { F10 = csub(F10, t0); F11 = csub(F11, t1); }
        else       { F10 = cadd(F10, t0); F11 = cadd(F11, t1); }
    }
    const float cq = cq1, sq = sq1, cr = c1, sr = s1;
    cx Du[2] = { cx{1.f+cq,  sq}, cx{1.f-cq, -sq} };
    cx Dv[2] = { cx{1.f+cr,  sr}, cx{1.f-cr, -sr} };
    cx Fm[2][2] = { {F00, F01}, {F10, F11} };
    cx R[2][2];
    float invW = 0.f;
    cx M{0.f,0.f};
    #pragma unroll
    for (int i = 0; i < 2; ++i)
      #pragma unroll
      for (int k = 0; k < 2; ++k) {
        cx fb = Fm[i][k];
        cx Rik = cadd(cconj(fb), cscale(cmul(Du[i], Dv[k]), lam));
        R[i][k] = Rik;
        invW += 0.25f * (fb.x*fb.x + fb.y*fb.y);
        M = cadd(M, cscale(cmul(fb, Rik), 0.25f));
      }
    cx V = cscale(M, 1.0f / (invW + lam));
    float inv_lam = 1.0f / lam;
    cx G[2][2];
    #pragma unroll
    for (int i = 0; i < 2; ++i)
      #pragma unroll
      for (int k = 0; k < 2; ++k)
        G[i][k] = cscale(csub(R[i][k], cmul(cconj(Fm[i][k]), V)), inv_lam);

    cx G00 = G[0][0], G01 = G[0][1], G10 = G[1][0], G11 = G[1][1];
    cx Gh00 = cadd(cadd(G00,G01), cadd(G10,G11));
    cx Gh01 = cadd(csub(G00,G01), csub(G10,G11));
    cx Gh10 = csub(cadd(G00,G01), cadd(G10,G11));
    cx Gh11 = csub(csub(G00,G01), csub(G10,G11));
    cx phq = cx{cq, -sq};
    cx phr = cx{cr, -sr};
    cx H0 = Gh00;
    cx H1 = cmul(Gh01, phr);
    cx H2 = cmul(Gh10, phq);
    cx H3 = cmul(Gh11, cmul(phq, phr));

    const float scale = 1.0f / 65536.0f;   // ifft 1/(128*128) and 1/4 polyphase mean
    float2 kAv = make_float2((H0.x - H1.y)*scale, (H0.y + H1.x)*scale);
    float2 kBv = make_float2((H2.x - H3.y)*scale, (H2.y + H3.x)*scale);
    int o = (c << 14) + p;                 // contiguous across tid -> coalesced
    KA[o] = kAv;
    KB[o] = kBv;
}

#define ST2 129   // float2 stride: odd -> both row & col passes at bank-bandwidth minimum

template<int AXIS> __device__ __forceinline__ int laddr(int line, int i){
    return AXIS ? (i*ST2 + line) : (line*ST2 + i);
}

// Forward DIF, fused stages (S, S+1). S in {0,2,4}. 4096 quartets, 4/thread.
template<int AXIS, int S>
__device__ __forceinline__ void fwd_pair(float2* Sm, const float2* TW, int tid)
{
    const int h  = 64 >> S;
    const int hh = 32 >> S;
    #pragma unroll
    for (int it = 0; it < 4; ++it) {
        int qid  = it*1024 + tid;
        int line = qid & 127;
        int t    = qid >> 7;
        int blk  = t >> (5 - S);
        int j    = t & (hh - 1);
        int i0   = (blk << (7 - S)) + j;
        int a0 = laddr<AXIS>(line, i0);
        int a1 = laddr<AXIS>(line, i0 + hh);
        int a2 = laddr<AXIS>(line, i0 + h);
        int a3 = laddr<AXIS>(line, i0 + h + hh);
        float2 e0 = Sm[a0], e1 = Sm[a1], e2 = Sm[a2], e3 = Sm[a3];
        float2 w0 = TW[j << S], w1 = TW[(j << S) + 32], w2 = TW[j << (S + 1)];
        float2 u0 = caddf(e0, e2), d0 = cmulf(csubf(e0, e2), w0);
        float2 u1 = caddf(e1, e3), d1 = cmulf(csubf(e1, e3), w1);
        Sm[a0] = caddf(u0, u1);
        Sm[a1] = cmulf(csubf(u0, u1), w2);
        Sm[a2] = caddf(d0, d1);
        Sm[a3] = cmulf(csubf(d0, d1), w2);
    }
}

// Inverse DIT, fused stages (S, S+1). conj twiddles.
template<int AXIS, int S>
__device__ __forceinline__ void inv_pair(float2* Sm, const float2* TW, int tid)
{
    const int h = 1 << S;
    #pragma unroll
    for (int it = 0; it < 4; ++it) {
        int qid  = it*1024 + tid;
        int line = qid & 127;
        int t    = qid >> 7;
        int blk  = t >> S;
        int j    = t & (h - 1);
        int base = (blk << (S + 2)) + j;
        int a0 = laddr<AXIS>(line, base);
        int a1 = laddr<AXIS>(line, base + h);
        int a2 = laddr<AXIS>(line, base + 2*h);
        int a3 = laddr<AXIS>(line, base + 3*h);
        float2 e0 = Sm[a0], e1 = Sm[a1], e2 = Sm[a2], e3 = Sm[a3];
        float2 cw0 = TW[j << (6 - S)];
        float2 cw1 = TW[j << (5 - S)];
        float2 cw2 = TW[(j << (5 - S)) + 32];
        float2 t1 = cmulcf(e1, cw0);
        float2 A0 = caddf(e0, t1), A1 = csubf(e0, t1);
        float2 t2 = cmulcf(e3, cw0);
        float2 A2 = caddf(e2, t2), A3 = csubf(e2, t2);
        float2 u = cmulcf(A2, cw1);
        Sm[a0] = caddf(A0, u);
        Sm[a2] = csubf(A0, u);
        float2 v = cmulcf(A3, cw2);
        Sm[a1] = caddf(A1, v);
        Sm[a3] = csubf(A1, v);
    }
}

__global__ __launch_bounds__(1024, 4)
void converse_main(const float* __restrict__ x, const float* __restrict__ bias,
                   const float2* __restrict__ KA, const float2* __restrict__ KB,
                   float* __restrict__ out)
{
    __shared__ float2 S[128 * ST2];
    __shared__ float2 TW[64];

    const int tid = threadIdx.x;
    const int bc  = blockIdx.x;       // [0,256) = b*64 + c
    const int c   = bc & 63;

    if (tid < 64) {
        float s_, c_;
        __sincosf(-6.28318530717958647692f * (float)tid * (1.0f/128.0f), &s_, &c_);
        TW[tid] = make_float2(c_, s_);
    }

    // ---- load x[b,c] as {x, 0} (contiguous float2 writes, conflict-free) ----
    const float* xp = x + (size_t)bc * 16384;
    #pragma unroll
    for (int it = 0; it < 16; ++it) {
        int n = it * 1024 + tid;
        S[(n >> 7) * ST2 + (n & 127)] = make_float2(xp[n], 0.0f);
    }

    // ---- prefetch KA into regs; loads ride across the whole forward FFT ----
    const float2* KpA = KA + (size_t)c * 16384;
    const float2* KpB = KB + (size_t)c * 16384;
    const int nn = tid & 127;
    const int t7 = tid >> 7;
    const int kbase = t7*256 + nn;
    float2 kr[16];
    #pragma unroll
    for (int it = 0; it < 8; ++it) {
        kr[2*it]   = KpA[it*2048 + kbase];
        kr[2*it+1] = KpA[it*2048 + kbase + 128];
    }
    barrier_lds();

    // ---- forward rows (along n): fused (0,1),(2,3),(4,5), single 6 ----
    fwd_pair<0,0>(S, TW, tid); barrier_lds();
    fwd_pair<0,2>(S, TW, tid); barrier_lds();
    fwd_pair<0,4>(S, TW, tid); barrier_lds();
    #pragma unroll
    for (int it = 0; it < 8; ++it) {     // stage 6: pairs (2k,2k+1), twiddle 1
        int g = it*1024 + tid;
        int line = g & 127, k = g >> 7;
        int a = line*ST2 + 2*k;
        float2 u = S[a], v = S[a+1];
        S[a]   = caddf(u, v);
        S[a+1] = csubf(u, v);
    }
    barrier_lds();

    // ---- forward cols (along m): fused (0,1),(2,3),(4,5) ----
    fwd_pair<1,0>(S, TW, tid); barrier_lds();
    fwd_pair<1,2>(S, TW, tid); barrier_lds();
    fwd_pair<1,4>(S, TW, tid); barrier_lds();

    // ---- forward col stage 6 into registers (spectrum kept for both passes) ----
    float2 sA[8], sB[8];
    #pragma unroll
    for (int it = 0; it < 8; ++it) {
        int g = it*1024 + tid;
        int nnl = g & 127, j = g >> 7;
        int a = (2*j)*ST2 + nnl;
        float2 u = S[a], v = S[a + ST2];
        sA[it] = caddf(u, v);
        sB[it] = csubf(u, v);
    }
    // no barrier needed: each thread re-writes only its own addresses in the mult

    const float bv = bias[c];
    float* op = out + (size_t)bc * 65536;

    // ================= pass 0 (KA, even output rows) =================
    #pragma unroll
    for (int it = 0; it < 8; ++it) {     // K-mult fused with inverse col stage 0
        int j = it*8 + t7;
        float2 w0 = cmulf(sA[it], kr[2*it]);
        float2 w1 = cmulf(sB[it], kr[2*it+1]);
        int a = (2*j)*ST2 + nn;
        S[a]       = caddf(w0, w1);
        S[a + ST2] = csubf(w0, w1);
    }
    // prefetch KB into the same regs; rides across pass-0 inverse FFT + stores
    #pragma unroll
    for (int it = 0; it < 8; ++it) {
        kr[2*it]   = KpB[it*2048 + kbase];
        kr[2*it+1] = KpB[it*2048 + kbase + 128];
    }
    barrier_lds();

    inv_pair<1,1>(S, TW, tid); barrier_lds();
    inv_pair<1,3>(S, TW, tid); barrier_lds();
    inv_pair<1,5>(S, TW, tid); barrier_lds();
    inv_pair<0,0>(S, TW, tid); barrier_lds();
    inv_pair<0,2>(S, TW, tid); barrier_lds();
    inv_pair<0,4>(S, TW, tid); barrier_lds();

    #pragma unroll
    for (int it = 0; it < 8; ++it) {     // inverse row stage 6 fused with store
        int g = it*1024 + tid;
        int j = g & 63, m = g >> 6;
        int a = m*ST2 + j;
        float2 u = S[a], v = S[a + 64];
        float2 t = cmulcf(v, TW[j]);
        float2 o0 = caddf(u, t);
        float2 o1 = csubf(u, t);
        size_t ro = (size_t)(2*m) * 256;
        *(float2*)(op + ro + 2*j)       = make_float2(o0.x + bv, o0.y + bv);
        *(float2*)(op + ro + 2*j + 128) = make_float2(o1.x + bv, o1.y + bv);
    }
    barrier_lds();   // protect S (ds_reads retired); global stores stay in flight

    // ================= pass 1 (KB, odd output rows) =================
    #pragma unroll
    for (int it = 0; it < 8; ++it) {
        int j = it*8 + t7;
        float2 w0 = cmulf(sA[it], kr[2*it]);
        float2 w1 = cmulf(sB[it], kr[2*it+1]);
        int a = (2*j)*ST2 + nn;
        S[a]       = caddf(w0, w1);
        S[a + ST2] = csubf(w0, w1);
    }
    barrier_lds();

    inv_pair<1,1>(S, TW, tid); barrier_lds();
    inv_pair<1,3>(S, TW, tid); barrier_lds();
    inv_pair<1,5>(S, TW, tid); barrier_lds();
    inv_pair<0,0>(S, TW, tid); barrier_lds();
    inv_pair<0,2>(S, TW, tid); barrier_lds();
    inv_pair<0,4>(S, TW, tid); barrier_lds();

    #pragma unroll
    for (int it = 0; it < 8; ++it) {
        int g = it*1024 + tid;
        int j = g & 63, m = g >> 6;
        int a = m*ST2 + j;
        float2 u = S[a], v = S[a + 64];
        float2 t = cmulcf(v, TW[j]);
        float2 o0 = caddf(u, t);
        float2 o1 = csubf(u, t);
        size_t ro = (size_t)(2*m + 1) * 256;
        *(float2*)(op + ro + 2*j)       = make_float2(o0.x + bv, o0.y + bv);
        *(float2*)(op + ro + 2*j + 128) = make_float2(o1.x + bv, o1.y + bv);
    }
}

extern "C" void kernel_launch(void* const* d_in, const int* in_sizes, int n_in,
                              void* d_out, int out_size, void* d_ws, size_t ws_size,
                              hipStream_t stream)
{
    const float* x      = (const float*)d_in[0];   // [4,64,128,128]
    const float* weight = (const float*)d_in[1];   // [1,64,5,5]
    const float* bias   = (const float*)d_in[2];   // [1,64,1,1]
    const float* lam    = (const float*)d_in[3];   // [1,1,1,1]
    float* out = (float*)d_out;                    // [4,64,256,256]

    float2* KA = (float2*)d_ws;                    // 8 MB
    float2* KB = KA + (size_t)64 * 16384;          // 8 MB

    hipLaunchKernelGGL(precompute_K, dim3(4096), dim3(256), 0, stream,
                       weight, lam, KA, KB);
    hipLaunchKernelGGL(converse_main, dim3(256), dim3(1024), 0, stream,
                       x, bias, KA, KB, out);
}